// Round 8
// baseline (674.603 us; speedup 1.0000x reference)
//
#include <hip/hip_runtime.h>
#include <hip/hip_bf16.h>
#include <stdint.h>

#define T_TOK 2048
#define HDIM  1024
#define IDIM  3584
#define NEXP  8
#define NROWS 4096   // T_TOK * TOP_K
#define CHB   65536  // LDS chunk bytes: 128 rows x 256 k bf16 (512B/row)

typedef __attribute__((ext_vector_type(8))) short bf16x8;
typedef __attribute__((ext_vector_type(4))) float f32x4;

typedef __attribute__((address_space(3))) unsigned lds_u32;
typedef const __attribute__((address_space(1))) unsigned glb_u32;

#define MFMA16 __builtin_amdgcn_mfma_f32_16x16x32_bf16

__device__ __forceinline__ unsigned short f2bf(float f){
  union { float f; unsigned u; } v; v.f = f;
  unsigned r = v.u + 0x7FFFu + ((v.u >> 16) & 1u);   // RNE
  return (unsigned short)(r >> 16);
}
__device__ __forceinline__ bf16x8 pack8(float4 lo, float4 hi){
  union { __hip_bfloat162 b2[4]; bf16x8 v; } u;
  u.b2[0] = __float22bfloat162_rn(float2{lo.x, lo.y});
  u.b2[1] = __float22bfloat162_rn(float2{lo.z, lo.w});
  u.b2[2] = __float22bfloat162_rn(float2{hi.x, hi.y});
  u.b2[3] = __float22bfloat162_rn(float2{hi.z, hi.w});
  return u.v;
}

// ---------------- Kernel 1: RMSNorm + router ----------------
__global__ __launch_bounds__(256) void k_rms_router(
    const float* __restrict__ x, const float* __restrict__ rmsw,
    const float* __restrict__ gw, unsigned short* __restrict__ h_bf,
    int* __restrict__ topk_i, float* __restrict__ topk_w, int* __restrict__ count)
{
  const int t = blockIdx.x, tid = threadIdx.x;
  const int lane = tid & 63, wid = tid >> 6;
  float4 x4 = reinterpret_cast<const float4*>(x)[t*256 + tid];
  float ss = x4.x*x4.x + x4.y*x4.y + x4.z*x4.z + x4.w*x4.w;
  #pragma unroll
  for (int o = 32; o >= 1; o >>= 1) ss += __shfl_xor(ss, o);
  __shared__ float sred[4];
  __shared__ float slog[32];
  if (lane == 0) sred[wid] = ss;
  __syncthreads();
  float inv = rsqrtf((sred[0]+sred[1]+sred[2]+sred[3]) * (1.0f/HDIM) + 1e-6f);
  float4 w4 = reinterpret_cast<const float4*>(rmsw)[tid];
  float h0 = x4.x*inv*w4.x, h1 = x4.y*inv*w4.y, h2 = x4.z*inv*w4.z, h3 = x4.w*inv*w4.w;
  ushort4 hb; hb.x = f2bf(h0); hb.y = f2bf(h1); hb.z = f2bf(h2); hb.w = f2bf(h3);
  reinterpret_cast<ushort4*>(h_bf)[t*256 + tid] = hb;
  #pragma unroll
  for (int e = 0; e < NEXP; e++){
    float4 g4 = reinterpret_cast<const float4*>(gw)[e*256 + tid];
    float v = h0*g4.x + h1*g4.y + h2*g4.z + h3*g4.w;
    #pragma unroll
    for (int o = 32; o >= 1; o >>= 1) v += __shfl_xor(v, o);
    if (lane == 0) slog[e*4 + wid] = v;
  }
  __syncthreads();
  if (tid == 0){
    float lg[NEXP];
    #pragma unroll
    for (int e = 0; e < NEXP; e++) lg[e] = slog[e*4]+slog[e*4+1]+slog[e*4+2]+slog[e*4+3];
    int i0 = 0;
    for (int e = 1; e < NEXP; e++) if (lg[e] > lg[i0]) i0 = e;   // ties -> lowest index
    int i1 = -1;
    for (int e = 0; e < NEXP; e++){ if (e == i0) continue; if (i1 < 0 || lg[e] > lg[i1]) i1 = e; }
    float m  = fmaxf(lg[i0], lg[i1]);
    float e0 = expf(lg[i0]-m), e1 = expf(lg[i1]-m);
    float s  = e0 + e1;
    topk_i[t*2] = i0; topk_i[t*2+1] = i1;
    topk_w[t*2] = e0/s; topk_w[t*2+1] = e1/s;
    atomicAdd(&count[i0], 1); atomicAdd(&count[i1], 1);
  }
}

// ---------------- Kernel 2: offsets ----------------
__global__ void k_scan(const int* __restrict__ count, int* __restrict__ offset){
  if (threadIdx.x == 0){
    int o = 0;
    for (int e = 0; e < NEXP; e++){ offset[e] = o; o += count[e]; }
  }
}

// ---------------- Kernel 3: scatter ----------------
__global__ __launch_bounds__(256) void k_scatter(
    const int* __restrict__ topk_i, const float* __restrict__ topk_w,
    const int* __restrict__ offset, int* __restrict__ cursor,
    int* __restrict__ token_of_row, float* __restrict__ wrow, int* __restrict__ slot_of)
{
  int t = blockIdx.x*256 + threadIdx.x;
  if (t >= T_TOK) return;
  #pragma unroll
  for (int k = 0; k < 2; k++){
    int e = topk_i[t*2+k];
    int pos = atomicAdd(&cursor[e], 1);
    int row = offset[e] + pos;
    token_of_row[row] = t;
    wrow[row] = topk_w[t*2+k];
    slot_of[t*2+k] = row;
  }
}

// ---------------- Kernel 4: fused w1/w3 GEMM + SwiGLU ----------------
// Block 128 rows x 128 I-cols (dual gemm), 512 thr / 8 waves (2 row x 4 col).
// A: K-chunks of 256 in LDS (dbuf, global_load_lds, pre-swizzled src).
// B: direct global->reg per wave (exclusive 32 cols), 2-step static pipeline.
// Barriers: 1 per chunk (4 total). No per-K-step barriers.
__global__ __launch_bounds__(512, 2) void k_mlp_in(
    const unsigned short* __restrict__ h_bf, const float* __restrict__ w1,
    const float* __restrict__ w3, const int* __restrict__ token_of_row,
    const int* __restrict__ count, const int* __restrict__ offset,
    unsigned short* __restrict__ act)
{
  // d = 8*q + e : e pins XCD; q = panel*5 + rowtile (same-panel row-tiles adjacent)
  const int d = blockIdx.x;
  const int e = d & 7;
  const int q = d >> 3;
  const int rt = q % 5;
  const int panel = q / 5;               // 0..27
  const int cnt = count[e];
  if (rt * 128 >= cnt) return;
  const int off = offset[e], row0 = off + rt*128, rend = off + cnt;
  const int col0 = panel * 128;
  const int tid = threadIdx.x, lane = tid & 63, wave = tid >> 6;
  const int wr = wave >> 2, wc = wave & 3;

  __shared__ __align__(16) char sA[2*CHB];   // [buf][128 rows][512B], slot-swizzled

  // ---- A staging: thread t stages rows i*16 + (t>>5), phys slot t&31 ----
  const unsigned short* asrc[8];
  #pragma unroll
  for (int i = 0; i < 8; i++){
    int row  = i*16 + (tid >> 5);
    int phys = tid & 31;
    int logs = (phys & 24) | ((phys ^ row) & 7);   // involution swizzle
    int tok  = token_of_row[min(row0 + row, NROWS-1)];
    asrc[i] = h_bf + (size_t)tok*HDIM + logs*8;
  }
  #define ISSUE_A(c, b) { _Pragma("unroll")                                          \
    for (int i = 0; i < 8; i++)                                                      \
      __builtin_amdgcn_global_load_lds((glb_u32*)(const void*)(asrc[i] + (c)*256),   \
          (lds_u32*)(void*)(sA + (b)*CHB + i*8192 + tid*16), 16, 0, 0); }

  // ---- B: per-lane row pointers (wave-exclusive 32 cols) ----
  const float* b1p = w1 + ((size_t)e*IDIM + col0 + wc*32 + (lane&15))*HDIM + (lane>>4)*8;
  const float* b3p = w3 + ((size_t)e*IDIM + col0 + wc*32 + (lane&15))*HDIM + (lane>>4)*8;

  float4 s1[2][2][2], s3[2][2][2];   // [set][n][half] -- all indices literal
  #define LOAD_B(p, kk) { _Pragma("unroll")                                          \
    for (int n = 0; n < 2; n++){                                                     \
      const float4* q1 = reinterpret_cast<const float4*>(b1p + (size_t)n*16*HDIM + (size_t)(kk)*32); \
      s1[p][n][0] = q1[0]; s1[p][n][1] = q1[1];                                      \
      const float4* q3 = reinterpret_cast<const float4*>(b3p + (size_t)n*16*HDIM + (size_t)(kk)*32); \
      s3[p][n][0] = q3[0]; s3[p][n][1] = q3[1]; } }

  f32x4 acc1[4][2], acc3[4][2];
  #pragma unroll
  for (int m = 0; m < 4; m++)
    #pragma unroll
    for (int n = 0; n < 2; n++){
      acc1[m][n] = (f32x4){0.f,0.f,0.f,0.f};
      acc3[m][n] = (f32x4){0.f,0.f,0.f,0.f};
    }

  // One K-step: consume set p (holds kk), prefetch kk+2 into p, 16 MFMA.
  #define STEP(s, p, b, kpre) {                                                      \
    bf16x8 f1_0 = pack8(s1[p][0][0], s1[p][0][1]);                                   \
    bf16x8 f1_1 = pack8(s1[p][1][0], s1[p][1][1]);                                   \
    bf16x8 f3_0 = pack8(s3[p][0][0], s3[p][0][1]);                                   \
    bf16x8 f3_1 = pack8(s3[p][1][0], s3[p][1][1]);                                   \
    if ((kpre) < HDIM/32) LOAD_B(p, kpre);                                           \
    bf16x8 af[4];                                                                    \
    _Pragma("unroll")                                                                \
    for (int m = 0; m < 4; m++){                                                     \
      int row  = wr*64 + m*16 + (lane & 15);                                         \
      int slot = (s)*4 + (lane >> 4);                                                \
      int phys = (slot & 24) | ((slot ^ row) & 7);                                   \
      af[m] = *reinterpret_cast<const bf16x8*>(sA + (b)*CHB + row*512 + phys*16);    \
    }                                                                                \
    _Pragma("unroll")                                                                \
    for (int m = 0; m < 4; m++){                                                     \
      acc1[m][0] = MFMA16(af[m], f1_0, acc1[m][0], 0,0,0);                           \
      acc1[m][1] = MFMA16(af[m], f1_1, acc1[m][1], 0,0,0);                           \
      acc3[m][0] = MFMA16(af[m], f3_0, acc3[m][0], 0,0,0);                           \
      acc3[m][1] = MFMA16(af[m], f3_1, acc3[m][1], 0,0,0);                           \
    } }

  // prologue: A chunk0, B steps 0,1; wait A (16 B-loads younger), barrier
  ISSUE_A(0, 0);
  LOAD_B(0, 0);
  LOAD_B(1, 1);
  __builtin_amdgcn_sched_barrier(0);
  asm volatile("s_waitcnt vmcnt(16)" ::: "memory");
  __builtin_amdgcn_sched_barrier(0);
  __builtin_amdgcn_s_barrier();

  for (int c = 0; c < 4; c++){
    const int b = c & 1;
    if (c < 3) ISSUE_A(c+1, b^1);          // lands during this chunk's 8 steps
    const int k0 = c*8;
    STEP(0, 0, b, k0+2);  STEP(1, 1, b, k0+3);
    STEP(2, 0, b, k0+4);  STEP(3, 1, b, k0+5);
    STEP(4, 0, b, k0+6);  STEP(5, 1, b, k0+7);
    STEP(6, 0, b, k0+8);  STEP(7, 1, b, k0+9);
    if (c < 3){
      __builtin_amdgcn_sched_barrier(0);
      asm volatile("s_waitcnt vmcnt(16)" ::: "memory");  // 16 youngest = B prefetches; waits A(c+1)
      __builtin_amdgcn_sched_barrier(0);
      __builtin_amdgcn_s_barrier();
    }
  }

  // epilogue: silu(a)*g -> bf16
  const int lcol = lane & 15, lrow4 = (lane >> 4) * 4;
  #pragma unroll
  for (int m = 0; m < 4; m++){
    #pragma unroll
    for (int n = 0; n < 2; n++){
      int gcol = col0 + wc*32 + n*16 + lcol;
      #pragma unroll
      for (int r = 0; r < 4; r++){
        int grow = row0 + wr*64 + m*16 + lrow4 + r;
        if (grow < rend){
          float a = acc1[m][n][r], g = acc3[m][n][r];
          float sig = 1.0f / (1.0f + __expf(-a));
          act[(size_t)grow*IDIM + gcol] = f2bf(a * sig * g);
        }
      }
    }
  }
  #undef ISSUE_A
  #undef LOAD_B
  #undef STEP
}

// ---------------- Kernel 5: w2 GEMM (same barrier-light scheme) ----------------
// Block 128 rows x 128 H-cols, K=3584 in 14 chunks of 256.
__global__ __launch_bounds__(512, 2) void k_mlp_out(
    const unsigned short* __restrict__ act, const float* __restrict__ w2,
    const float* __restrict__ wrow, const int* __restrict__ count,
    const int* __restrict__ offset, float* __restrict__ eo)
{
  const int d = blockIdx.x;
  const int e = d & 7;
  const int q = d >> 3;
  const int rt = q % 5;
  const int panel = q / 5;               // 0..7
  const int cnt = count[e];
  if (rt * 128 >= cnt) return;
  const int off = offset[e], row0 = off + rt*128, rend = off + cnt;
  const int col0 = panel * 128;
  const int tid = threadIdx.x, lane = tid & 63, wave = tid >> 6;
  const int wr = wave >> 2, wc = wave & 3;

  __shared__ __align__(16) char sA[2*CHB];

  const unsigned short* asrc[8];
  #pragma unroll
  for (int i = 0; i < 8; i++){
    int row  = i*16 + (tid >> 5);
    int phys = tid & 31;
    int logs = (phys & 24) | ((phys ^ row) & 7);
    int r    = min(row0 + row, NROWS-1);
    asrc[i] = act + (size_t)r*IDIM + logs*8;
  }
  #define ISSUE_A(c, b) { _Pragma("unroll")                                          \
    for (int i = 0; i < 8; i++)                                                      \
      __builtin_amdgcn_global_load_lds((glb_u32*)(const void*)(asrc[i] + (c)*256),   \
          (lds_u32*)(void*)(sA + (b)*CHB + i*8192 + tid*16), 16, 0, 0); }

  const float* b2p = w2 + ((size_t)e*HDIM + col0 + wc*32 + (lane&15))*IDIM + (lane>>4)*8;

  float4 s2[2][2][2];
  #define LOAD_B(p, kk) { _Pragma("unroll")                                          \
    for (int n = 0; n < 2; n++){                                                     \
      const float4* qq = reinterpret_cast<const float4*>(b2p + (size_t)n*16*IDIM + (size_t)(kk)*32); \
      s2[p][n][0] = qq[0]; s2[p][n][1] = qq[1]; } }

  f32x4 acc[4][2];
  #pragma unroll
  for (int m = 0; m < 4; m++)
    #pragma unroll
    for (int n = 0; n < 2; n++) acc[m][n] = (f32x4){0.f,0.f,0.f,0.f};

  #define STEP(s, p, b, kpre) {                                                      \
    bf16x8 f0 = pack8(s2[p][0][0], s2[p][0][1]);                                     \
    bf16x8 f1 = pack8(s2[p][1][0], s2[p][1][1]);                                     \
    if ((kpre) < IDIM/32) LOAD_B(p, kpre);                                           \
    bf16x8 af[4];                                                                    \
    _Pragma("unroll")                                                                \
    for (int m = 0; m < 4; m++){                                                     \
      int row  = wr*64 + m*16 + (lane & 15);                                         \
      int slot = (s)*4 + (lane >> 4);                                                \
      int phys = (slot & 24) | ((slot ^ row) & 7);                                   \
      af[m] = *reinterpret_cast<const bf16x8*>(sA + (b)*CHB + row*512 + phys*16);    \
    }                                                                                \
    _Pragma("unroll")                                                                \
    for (int m = 0; m < 4; m++){                                                     \
      acc[m][0] = MFMA16(af[m], f0, acc[m][0], 0,0,0);                               \
      acc[m][1] = MFMA16(af[m], f1, acc[m][1], 0,0,0);                               \
    } }

  ISSUE_A(0, 0);
  LOAD_B(0, 0);
  LOAD_B(1, 1);
  __builtin_amdgcn_sched_barrier(0);
  asm volatile("s_waitcnt vmcnt(8)" ::: "memory");
  __builtin_amdgcn_sched_barrier(0);
  __builtin_amdgcn_s_barrier();

  for (int c = 0; c < 14; c++){
    const int b = c & 1;
    if (c < 13) ISSUE_A(c+1, b^1);
    const int k0 = c*8;
    STEP(0, 0, b, k0+2);  STEP(1, 1, b, k0+3);
    STEP(2, 0, b, k0+4);  STEP(3, 1, b, k0+5);
    STEP(4, 0, b, k0+6);  STEP(5, 1, b, k0+7);
    STEP(6, 0, b, k0+8);  STEP(7, 1, b, k0+9);
    if (c < 13){
      __builtin_amdgcn_sched_barrier(0);
      asm volatile("s_waitcnt vmcnt(8)" ::: "memory");
      __builtin_amdgcn_sched_barrier(0);
      __builtin_amdgcn_s_barrier();
    }
  }

  const int lcol = lane & 15, lrow4 = (lane >> 4) * 4;
  #pragma unroll
  for (int m = 0; m < 4; m++){
    #pragma unroll
    for (int n = 0; n < 2; n++){
      int gcol = col0 + wc*32 + n*16 + lcol;
      #pragma unroll
      for (int r = 0; r < 4; r++){
        int grow = row0 + wr*64 + m*16 + lrow4 + r;
        if (grow < rend){
          eo[(size_t)grow*HDIM + gcol] = acc[m][n][r] * wrow[grow];
        }
      }
    }
  }
  #undef ISSUE_A
  #undef LOAD_B
  #undef STEP
}

// ---------------- Kernel 6: combine + residual ----------------
__global__ __launch_bounds__(256) void k_combine(
    const float* __restrict__ x, const float* __restrict__ eo,
    const int* __restrict__ slot_of, float* __restrict__ out)
{
  const int t = blockIdx.x, tid = threadIdx.x;
  const int s0 = slot_of[t*2], s1 = slot_of[t*2+1];
  float4 xv = reinterpret_cast<const float4*>(x)[t*256 + tid];
  float4 a  = reinterpret_cast<const float4*>(eo)[s0*256 + tid];
  float4 b  = reinterpret_cast<const float4*>(eo)[s1*256 + tid];
  float4 ov;
  ov.x = xv.x + a.x + b.x;
  ov.y = xv.y + a.y + b.y;
  ov.z = xv.z + a.z + b.z;
  ov.w = xv.w + a.w + b.w;
  reinterpret_cast<float4*>(out)[t*256 + tid] = ov;
}

extern "C" void kernel_launch(void* const* d_in, const int* in_sizes, int n_in,
                              void* d_out, int out_size, void* d_ws, size_t ws_size,
                              hipStream_t stream)
{
  const float* x    = (const float*)d_in[0];
  const float* rmsw = (const float*)d_in[1];
  const float* gw   = (const float*)d_in[2];
  const float* w1   = (const float*)d_in[3];
  const float* w2   = (const float*)d_in[4];
  const float* w3   = (const float*)d_in[5];
  float* out = (float*)d_out;

  char* ws = (char*)d_ws;
  size_t o = 0;
  auto alloc = [&](size_t bytes) -> void* {
    void* p = ws + o;
    o += (bytes + 255) & ~(size_t)255;
    return p;
  };
  unsigned short* h_bf   = (unsigned short*)alloc((size_t)T_TOK*HDIM*2);
  int*   topk_i          = (int*)  alloc(T_TOK*2*4);
  float* topk_w          = (float*)alloc(T_TOK*2*4);
  int*   counters        = (int*)  alloc(64*4);   // count[8], cursor[8], offset[8]
  int*   token_of_row    = (int*)  alloc(NROWS*4);
  float* wrow            = (float*)alloc(NROWS*4);
  int*   slot_of         = (int*)  alloc(T_TOK*2*4);
  unsigned short* act    = (unsigned short*)alloc((size_t)NROWS*IDIM*2);
  float* eo              = (float*)alloc((size_t)NROWS*HDIM*4);
  int* count  = counters;
  int* cursor = counters + 8;
  int* offset = counters + 16;

  hipMemsetAsync(counters, 0, 64*4, stream);
  k_rms_router<<<T_TOK, 256, 0, stream>>>(x, rmsw, gw, h_bf, topk_i, topk_w, count);
  k_scan<<<1, 64, 0, stream>>>(count, offset);
  k_scatter<<<(T_TOK+255)/256, 256, 0, stream>>>(topk_i, topk_w, offset, cursor,
                                                 token_of_row, wrow, slot_of);
  // mlp_in: 8 experts x 5 row-tiles x 28 col-panels = 1120 blocks (e = XCD pin)
  k_mlp_in <<<1120, 512, 0, stream>>>(h_bf, w1, w3, token_of_row, count, offset, act);
  // mlp_out: 8 experts x 5 row-tiles x 8 col-panels = 320 blocks
  k_mlp_out<<<320, 512, 0, stream>>>(act, w2, wrow, count, offset, eo);
  k_combine<<<T_TOK, 256, 0, stream>>>(x, eo, slot_of, out);
}

// Round 9
// 348.577 us; speedup vs baseline: 1.9353x; 1.9353x over previous
//
#include <hip/hip_runtime.h>
#include <hip/hip_bf16.h>
#include <stdint.h>

#define T_TOK 2048
#define HDIM  1024
#define IDIM  3584
#define NEXP  8
#define NROWS 4096   // T_TOK * TOP_K
#define WELEM 29360128  // elements per weight tensor (8*3584*1024)

typedef __attribute__((ext_vector_type(8))) short bf16x8;
typedef __attribute__((ext_vector_type(4))) float f32x4;
typedef __attribute__((ext_vector_type(4))) unsigned int u32x4;

typedef __attribute__((address_space(3))) unsigned lds_u32;
typedef const __attribute__((address_space(1))) unsigned glb_u32;

#define MFMA16 __builtin_amdgcn_mfma_f32_16x16x32_bf16

__device__ __forceinline__ unsigned short f2bf(float f){
  union { float f; unsigned u; } v; v.f = f;
  unsigned r = v.u + 0x7FFFu + ((v.u >> 16) & 1u);   // RNE
  return (unsigned short)(r >> 16);
}
__device__ __forceinline__ unsigned cvt2(float a, float b){
  __hip_bfloat162 h = __float22bfloat162_rn(float2{a, b});
  return *reinterpret_cast<unsigned*>(&h);
}
__device__ __forceinline__ bf16x8 pack8(float4 lo, float4 hi){
  union { __hip_bfloat162 b2[4]; bf16x8 v; } u;
  u.b2[0] = __float22bfloat162_rn(float2{lo.x, lo.y});
  u.b2[1] = __float22bfloat162_rn(float2{lo.z, lo.w});
  u.b2[2] = __float22bfloat162_rn(float2{hi.x, hi.y});
  u.b2[3] = __float22bfloat162_rn(float2{hi.z, hi.w});
  return u.v;
}

// ---------------- Kernel 1: RMSNorm + router ----------------
__global__ __launch_bounds__(256) void k_rms_router(
    const float* __restrict__ x, const float* __restrict__ rmsw,
    const float* __restrict__ gw, unsigned short* __restrict__ h_bf,
    int* __restrict__ topk_i, float* __restrict__ topk_w, int* __restrict__ count)
{
  const int t = blockIdx.x, tid = threadIdx.x;
  const int lane = tid & 63, wid = tid >> 6;
  float4 x4 = reinterpret_cast<const float4*>(x)[t*256 + tid];
  float ss = x4.x*x4.x + x4.y*x4.y + x4.z*x4.z + x4.w*x4.w;
  #pragma unroll
  for (int o = 32; o >= 1; o >>= 1) ss += __shfl_xor(ss, o);
  __shared__ float sred[4];
  __shared__ float slog[32];
  if (lane == 0) sred[wid] = ss;
  __syncthreads();
  float inv = rsqrtf((sred[0]+sred[1]+sred[2]+sred[3]) * (1.0f/HDIM) + 1e-6f);
  float4 w4 = reinterpret_cast<const float4*>(rmsw)[tid];
  float h0 = x4.x*inv*w4.x, h1 = x4.y*inv*w4.y, h2 = x4.z*inv*w4.z, h3 = x4.w*inv*w4.w;
  ushort4 hb; hb.x = f2bf(h0); hb.y = f2bf(h1); hb.z = f2bf(h2); hb.w = f2bf(h3);
  reinterpret_cast<ushort4*>(h_bf)[t*256 + tid] = hb;
  #pragma unroll
  for (int e = 0; e < NEXP; e++){
    float4 g4 = reinterpret_cast<const float4*>(gw)[e*256 + tid];
    float v = h0*g4.x + h1*g4.y + h2*g4.z + h3*g4.w;
    #pragma unroll
    for (int o = 32; o >= 1; o >>= 1) v += __shfl_xor(v, o);
    if (lane == 0) slog[e*4 + wid] = v;
  }
  __syncthreads();
  if (tid == 0){
    float lg[NEXP];
    #pragma unroll
    for (int e = 0; e < NEXP; e++) lg[e] = slog[e*4]+slog[e*4+1]+slog[e*4+2]+slog[e*4+3];
    int i0 = 0;
    for (int e = 1; e < NEXP; e++) if (lg[e] > lg[i0]) i0 = e;   // ties -> lowest index
    int i1 = -1;
    for (int e = 0; e < NEXP; e++){ if (e == i0) continue; if (i1 < 0 || lg[e] > lg[i1]) i1 = e; }
    float m  = fmaxf(lg[i0], lg[i1]);
    float e0 = expf(lg[i0]-m), e1 = expf(lg[i1]-m);
    float s  = e0 + e1;
    topk_i[t*2] = i0; topk_i[t*2+1] = i1;
    topk_w[t*2] = e0/s; topk_w[t*2+1] = e1/s;
    atomicAdd(&count[i0], 1); atomicAdd(&count[i1], 1);
  }
}

// ---------------- Kernel 2: offsets ----------------
__global__ void k_scan(const int* __restrict__ count, int* __restrict__ offset){
  if (threadIdx.x == 0){
    int o = 0;
    for (int e = 0; e < NEXP; e++){ offset[e] = o; o += count[e]; }
  }
}

// ---------------- Kernel 3: scatter ----------------
__global__ __launch_bounds__(256) void k_scatter(
    const int* __restrict__ topk_i, const float* __restrict__ topk_w,
    const int* __restrict__ offset, int* __restrict__ cursor,
    int* __restrict__ token_of_row, float* __restrict__ wrow, int* __restrict__ slot_of)
{
  int t = blockIdx.x*256 + threadIdx.x;
  if (t >= T_TOK) return;
  #pragma unroll
  for (int k = 0; k < 2; k++){
    int e = topk_i[t*2+k];
    int pos = atomicAdd(&cursor[e], 1);
    int row = offset[e] + pos;
    token_of_row[row] = t;
    wrow[row] = topk_w[t*2+k];
    slot_of[t*2+k] = row;
  }
}

// ---------------- Kernel: fp32 -> bf16 weight conversion (streaming) ----------------
__global__ __launch_bounds__(256) void k_cvt(
    const float4* __restrict__ src, uint2* __restrict__ dst, int n4)
{
  int stride = gridDim.x * blockDim.x;
  for (int i = blockIdx.x*blockDim.x + threadIdx.x; i < n4; i += stride){
    float4 v = src[i];
    dst[i] = make_uint2(cvt2(v.x, v.y), cvt2(v.z, v.w));
  }
}

// =====================================================================
// m97-replica path: bf16 weights, all staging via global_load_lds.
// Tile 128 rows x 64 cols, BK=64, 256 thr / 4 waves (2x2), wave 64x32.
// Staging: thread t stages (row/col = (t>>3)+32j, k-chunk g = (t&7)^((t>>3)&7))
//   -> LDS dest j*4096 + tid*16 (wave-linear); read phys slot = slot^(row&7).
// =====================================================================
__global__ __launch_bounds__(256, 3) void k_mlp_in_bf(
    const unsigned short* __restrict__ h_bf, const unsigned short* __restrict__ w1bf,
    const unsigned short* __restrict__ w3bf, const int* __restrict__ token_of_row,
    const int* __restrict__ count, const int* __restrict__ offset,
    unsigned short* __restrict__ act)
{
  // d = 8q + e: e pins XCD; q = panel*16 + rt so same-panel row-tiles adjacent.
  const int d = blockIdx.x;
  const int e = d & 7;
  const int q = d >> 3;           // 0..895
  const int panel = q >> 4;       // 0..55
  const int rt = q & 15;
  const int cnt = count[e];
  if (rt * 128 >= cnt) return;
  const int off = offset[e], row0 = off + rt*128, rend = off + cnt;
  const int col0 = panel * 64;
  const int tid = threadIdx.x, lane = tid & 63, wid = tid >> 6;
  const int wave_r = wid >> 1, wave_c = wid & 1;

  __shared__ __align__(16) char sA [128*128];  // 128 rows x 64 k bf16 (swizzled slots)
  __shared__ __align__(16) char sB1[64*128];   // 64 cols x 64 k bf16
  __shared__ __align__(16) char sB2[64*128];

  const int srow = tid >> 3;              // 0..31
  const int sg   = (tid & 7) ^ (srow & 7);  // logical k-chunk this thread stages

  const unsigned short* aptr[4];
  #pragma unroll
  for (int j = 0; j < 4; j++){
    int tok = token_of_row[min(row0 + srow + 32*j, NROWS-1)];
    aptr[j] = h_bf + (size_t)tok*HDIM + sg*8;
  }
  const unsigned short* b1ptr[2];
  const unsigned short* b3ptr[2];
  #pragma unroll
  for (int j = 0; j < 2; j++){
    int col = col0 + srow + 32*j;
    b1ptr[j] = w1bf + (size_t)(e*IDIM + col)*HDIM + sg*8;
    b3ptr[j] = w3bf + (size_t)(e*IDIM + col)*HDIM + sg*8;
  }

  #define ISSUE(kk) {                                                                \
    _Pragma("unroll")                                                                \
    for (int j = 0; j < 4; j++)                                                      \
      __builtin_amdgcn_global_load_lds((glb_u32*)(const void*)(aptr[j] + (kk)*64),   \
          (lds_u32*)(void*)(sA + j*4096 + tid*16), 16, 0, 0);                        \
    _Pragma("unroll")                                                                \
    for (int j = 0; j < 2; j++){                                                     \
      __builtin_amdgcn_global_load_lds((glb_u32*)(const void*)(b1ptr[j] + (kk)*64),  \
          (lds_u32*)(void*)(sB1 + j*4096 + tid*16), 16, 0, 0);                       \
      __builtin_amdgcn_global_load_lds((glb_u32*)(const void*)(b3ptr[j] + (kk)*64),  \
          (lds_u32*)(void*)(sB2 + j*4096 + tid*16), 16, 0, 0);                       \
    } }

  f32x4 acc1[4][2], acc3[4][2];
  #pragma unroll
  for (int m = 0; m < 4; m++)
    #pragma unroll
    for (int n = 0; n < 2; n++){
      acc1[m][n] = (f32x4){0.f,0.f,0.f,0.f};
      acc3[m][n] = (f32x4){0.f,0.f,0.f,0.f};
    }

  for (int kk = 0; kk < HDIM/64; kk++){
    ISSUE(kk);
    __syncthreads();          // drains vmcnt: tile kk ready (m97 pattern)
    #pragma unroll
    for (int ki = 0; ki < 2; ki++){
      bf16x8 af[4];
      #pragma unroll
      for (int m = 0; m < 4; m++){
        int row = wave_r*64 + m*16 + (lane & 15);
        int slot = ki*4 + (lane >> 4);
        af[m] = *reinterpret_cast<const bf16x8*>(sA + row*128 + ((slot ^ (row&7))<<4));
      }
      #pragma unroll
      for (int n = 0; n < 2; n++){
        int col = wave_c*32 + n*16 + (lane & 15);
        int slot = ki*4 + (lane >> 4);
        bf16x8 b1 = *reinterpret_cast<const bf16x8*>(sB1 + col*128 + ((slot ^ (col&7))<<4));
        bf16x8 b2 = *reinterpret_cast<const bf16x8*>(sB2 + col*128 + ((slot ^ (col&7))<<4));
        #pragma unroll
        for (int m = 0; m < 4; m++){
          acc1[m][n] = MFMA16(af[m], b1, acc1[m][n], 0,0,0);
          acc3[m][n] = MFMA16(af[m], b2, acc3[m][n], 0,0,0);
        }
      }
    }
    __syncthreads();          // reads done before next overwrite
  }

  const int lcol = lane & 15, lrow4 = (lane >> 4) * 4;
  #pragma unroll
  for (int m = 0; m < 4; m++){
    #pragma unroll
    for (int n = 0; n < 2; n++){
      int gcol = col0 + wave_c*32 + n*16 + lcol;
      #pragma unroll
      for (int r = 0; r < 4; r++){
        int grow = row0 + wave_r*64 + m*16 + lrow4 + r;
        if (grow < rend){
          float a = acc1[m][n][r], g = acc3[m][n][r];
          float sig = 1.0f / (1.0f + __expf(-a));
          act[(size_t)grow*IDIM + gcol] = f2bf(a * sig * g);
        }
      }
    }
  }
  #undef ISSUE
}

__global__ __launch_bounds__(256, 4) void k_mlp_out_bf(
    const unsigned short* __restrict__ act, const unsigned short* __restrict__ w2bf,
    const float* __restrict__ wrow, const int* __restrict__ count,
    const int* __restrict__ offset, float* __restrict__ eo)
{
  const int d = blockIdx.x;
  const int e = d & 7;
  const int q = d >> 3;           // 0..255
  const int panel = q >> 4;       // 0..15
  const int rt = q & 15;
  const int cnt = count[e];
  if (rt * 128 >= cnt) return;
  const int off = offset[e], row0 = off + rt*128, rend = off + cnt;
  const int col0 = panel * 64;
  const int tid = threadIdx.x, lane = tid & 63, wid = tid >> 6;
  const int wave_r = wid >> 1, wave_c = wid & 1;

  __shared__ __align__(16) char sA[128*128];
  __shared__ __align__(16) char sB[64*128];

  const int srow = tid >> 3;
  const int sg   = (tid & 7) ^ (srow & 7);

  const unsigned short* aptr[4];
  #pragma unroll
  for (int j = 0; j < 4; j++){
    int r = min(row0 + srow + 32*j, NROWS-1);
    aptr[j] = act + (size_t)r*IDIM + sg*8;
  }
  const unsigned short* bptr[2];
  #pragma unroll
  for (int j = 0; j < 2; j++){
    int col = col0 + srow + 32*j;
    bptr[j] = w2bf + (size_t)(e*HDIM + col)*IDIM + sg*8;
  }

  #define ISSUE(kk) {                                                                \
    _Pragma("unroll")                                                                \
    for (int j = 0; j < 4; j++)                                                      \
      __builtin_amdgcn_global_load_lds((glb_u32*)(const void*)(aptr[j] + (kk)*64),   \
          (lds_u32*)(void*)(sA + j*4096 + tid*16), 16, 0, 0);                        \
    _Pragma("unroll")                                                                \
    for (int j = 0; j < 2; j++)                                                      \
      __builtin_amdgcn_global_load_lds((glb_u32*)(const void*)(bptr[j] + (kk)*64),   \
          (lds_u32*)(void*)(sB + j*4096 + tid*16), 16, 0, 0); }

  f32x4 acc[4][2];
  #pragma unroll
  for (int m = 0; m < 4; m++)
    #pragma unroll
    for (int n = 0; n < 2; n++) acc[m][n] = (f32x4){0.f,0.f,0.f,0.f};

  for (int kk = 0; kk < IDIM/64; kk++){
    ISSUE(kk);
    __syncthreads();
    #pragma unroll
    for (int ki = 0; ki < 2; ki++){
      bf16x8 af[4];
      #pragma unroll
      for (int m = 0; m < 4; m++){
        int row = wave_r*64 + m*16 + (lane & 15);
        int slot = ki*4 + (lane >> 4);
        af[m] = *reinterpret_cast<const bf16x8*>(sA + row*128 + ((slot ^ (row&7))<<4));
      }
      #pragma unroll
      for (int n = 0; n < 2; n++){
        int col = wave_c*32 + n*16 + (lane & 15);
        int slot = ki*4 + (lane >> 4);
        bf16x8 fb = *reinterpret_cast<const bf16x8*>(sB + col*128 + ((slot ^ (col&7))<<4));
        #pragma unroll
        for (int m = 0; m < 4; m++)
          acc[m][n] = MFMA16(af[m], fb, acc[m][n], 0,0,0);
      }
    }
    __syncthreads();
  }

  const int lcol = lane & 15, lrow4 = (lane >> 4) * 4;
  #pragma unroll
  for (int m = 0; m < 4; m++){
    #pragma unroll
    for (int n = 0; n < 2; n++){
      int gcol = col0 + wave_c*32 + n*16 + lcol;
      #pragma unroll
      for (int r = 0; r < 4; r++){
        int grow = row0 + wave_r*64 + m*16 + lrow4 + r;
        if (grow < rend){
          eo[(size_t)grow*HDIM + gcol] = acc[m][n][r] * wrow[grow];
        }
      }
    }
  }
  #undef ISSUE
}

// =====================================================================
// Fallback path (ws too small for bf16 weights): R2's proven kernels.
// =====================================================================
__global__ __launch_bounds__(256, 2) void k_mlp_in_fb(
    const unsigned short* __restrict__ h_bf, const float* __restrict__ w1,
    const float* __restrict__ w3, const int* __restrict__ token_of_row,
    const int* __restrict__ count, const int* __restrict__ offset,
    unsigned short* __restrict__ act)
{
  int bx, by, bz;
  {
    int d = blockIdx.x + 16*(blockIdx.y + 56*blockIdx.z);
    int w = (d & 7)*896 + (d >> 3);
    bx = w & 15; int r = w >> 4; by = r % 56; bz = r / 56;
  }
  const int e = bz, tile = bx;
  const int cnt = count[e];
  if (tile * 128 >= cnt) return;
  const int off  = offset[e];
  const int row0 = off + tile*128;
  const int rend = off + cnt;
  const int col0 = by * 64;
  const int tid = threadIdx.x, lane = tid & 63, wid = tid >> 6;
  const int wave_r = wid >> 1, wave_c = wid & 1;

  __shared__ __align__(16) char sA [128*128];
  __shared__ __align__(16) char sB1[64*128];
  __shared__ __align__(16) char sB2[64*128];

  const int arow_base = tid >> 3;
  const int kseg = tid & 7;
  const unsigned short* aptr[4];
  #pragma unroll
  for (int j = 0; j < 4; j++){
    int r = row0 + arow_base + 32*j;
    aptr[j] = h_bf + (size_t)token_of_row[min(r, NROWS-1)]*HDIM + kseg*8;
  }
  const float* w1base = w1 + (size_t)e*IDIM*HDIM + (size_t)col0*HDIM + (size_t)arow_base*HDIM + kseg*8;
  const float* w3base = w3 + (size_t)e*IDIM*HDIM + (size_t)col0*HDIM + (size_t)arow_base*HDIM + kseg*8;

  u32x4  pa[4];
  float4 pb1[2][2], pb3[2][2];

  auto LOAD = [&](int kk){
    #pragma unroll
    for (int j = 0; j < 4; j++)
      pa[j] = *reinterpret_cast<const u32x4*>(aptr[j] + kk*64);
    #pragma unroll
    for (int j = 0; j < 2; j++){
      const float4* p1 = reinterpret_cast<const float4*>(w1base + (size_t)(32*j)*HDIM + kk*64);
      const float4* p3 = reinterpret_cast<const float4*>(w3base + (size_t)(32*j)*HDIM + kk*64);
      pb1[j][0] = p1[0]; pb1[j][1] = p1[1];
      pb3[j][0] = p3[0]; pb3[j][1] = p3[1];
    }
  };
  const int aswz = (kseg ^ (arow_base & 7)) << 4;
  auto STORE = [&](){
    #pragma unroll
    for (int j = 0; j < 4; j++)
      *reinterpret_cast<u32x4*>(sA + (arow_base + 32*j)*128 + aswz) = pa[j];
    #pragma unroll
    for (int j = 0; j < 2; j++){
      *reinterpret_cast<bf16x8*>(sB1 + (arow_base + 32*j)*128 + aswz) = pack8(pb1[j][0], pb1[j][1]);
      *reinterpret_cast<bf16x8*>(sB2 + (arow_base + 32*j)*128 + aswz) = pack8(pb3[j][0], pb3[j][1]);
    }
  };

  f32x4 acc_a[4][2], acc_g[4][2];
  #pragma unroll
  for (int m = 0; m < 4; m++)
    #pragma unroll
    for (int n = 0; n < 2; n++){
      acc_a[m][n] = (f32x4){0.f,0.f,0.f,0.f};
      acc_g[m][n] = (f32x4){0.f,0.f,0.f,0.f};
    }

  LOAD(0);
  for (int kk = 0; kk < HDIM/64; kk++){
    STORE();
    if (kk + 1 < HDIM/64) LOAD(kk+1);
    __syncthreads();
    #pragma unroll
    for (int ki = 0; ki < 2; ki++){
      bf16x8 af[4];
      #pragma unroll
      for (int m = 0; m < 4; m++){
        int row = wave_r*64 + m*16 + (lane&15);
        int slot = ki*4 + (lane>>4);
        af[m] = *reinterpret_cast<const bf16x8*>(sA + row*128 + ((slot ^ (row&7))<<4));
      }
      #pragma unroll
      for (int n = 0; n < 2; n++){
        int col = wave_c*32 + n*16 + (lane&15);
        int slot = ki*4 + (lane>>4);
        bf16x8 b1 = *reinterpret_cast<const bf16x8*>(sB1 + col*128 + ((slot ^ (col&7))<<4));
        bf16x8 b2 = *reinterpret_cast<const bf16x8*>(sB2 + col*128 + ((slot ^ (col&7))<<4));
        #pragma unroll
        for (int m = 0; m < 4; m++){
          acc_a[m][n] = MFMA16(af[m], b1, acc_a[m][n], 0,0,0);
          acc_g[m][n] = MFMA16(af[m], b2, acc_g[m][n], 0,0,0);
        }
      }
    }
    __syncthreads();
  }
  const int lcol = lane & 15, lrow4 = (lane >> 4) * 4;
  #pragma unroll
  for (int m = 0; m < 4; m++){
    #pragma unroll
    for (int n = 0; n < 2; n++){
      int gcol = col0 + wave_c*32 + n*16 + lcol;
      #pragma unroll
      for (int r = 0; r < 4; r++){
        int grow = row0 + wave_r*64 + m*16 + lrow4 + r;
        if (grow < rend){
          float a = acc_a[m][n][r], g = acc_g[m][n][r];
          float sig = 1.0f / (1.0f + __expf(-a));
          act[(size_t)grow*IDIM + gcol] = f2bf(a * sig * g);
        }
      }
    }
  }
}

__global__ __launch_bounds__(256, 3) void k_mlp_out_fb(
    const unsigned short* __restrict__ act, const float* __restrict__ w2,
    const float* __restrict__ wrow, const int* __restrict__ count,
    const int* __restrict__ offset, float* __restrict__ eo)
{
  int bx, by, bz;
  {
    int d = blockIdx.x + 16*(blockIdx.y + 16*blockIdx.z);
    int w = (d & 7)*256 + (d >> 3);
    bx = w & 15; int r = w >> 4; by = r & 15; bz = r >> 4;
  }
  const int e = bz, tile = bx;
  const int cnt = count[e];
  if (tile*128 >= cnt) return;
  const int off = offset[e], row0 = off + tile*128, rend = off + cnt;
  const int col0 = by * 64;
  const int tid = threadIdx.x, lane = tid & 63, wid = tid >> 6;
  const int wave_r = wid >> 1, wave_c = wid & 1;

  __shared__ __align__(16) char sA[128*128];
  __shared__ __align__(16) char sB[64*128];

  const int arow_base = tid >> 3, kseg = tid & 7;
  const unsigned short* aptr[4];
  #pragma unroll
  for (int j = 0; j < 4; j++){
    int r = min(row0 + arow_base + 32*j, NROWS-1);
    aptr[j] = act + (size_t)r * IDIM + kseg*8;
  }
  const float* w2base = w2 + (size_t)e*HDIM*IDIM + (size_t)col0*IDIM + (size_t)arow_base*IDIM + kseg*8;

  u32x4  pa[4];
  float4 pb[2][2];

  auto LOAD = [&](int kk){
    #pragma unroll
    for (int j = 0; j < 4; j++)
      pa[j] = *reinterpret_cast<const u32x4*>(aptr[j] + kk*64);
    #pragma unroll
    for (int j = 0; j < 2; j++){
      const float4* p = reinterpret_cast<const float4*>(w2base + (size_t)(32*j)*IDIM + kk*64);
      pb[j][0] = p[0]; pb[j][1] = p[1];
    }
  };
  const int aswz = (kseg ^ (arow_base & 7)) << 4;
  auto STORE = [&](){
    #pragma unroll
    for (int j = 0; j < 4; j++)
      *reinterpret_cast<u32x4*>(sA + (arow_base + 32*j)*128 + aswz) = pa[j];
    #pragma unroll
    for (int j = 0; j < 2; j++)
      *reinterpret_cast<bf16x8*>(sB + (arow_base + 32*j)*128 + aswz) = pack8(pb[j][0], pb[j][1]);
  };

  f32x4 acc[4][2];
  #pragma unroll
  for (int m = 0; m < 4; m++)
    #pragma unroll
    for (int n = 0; n < 2; n++) acc[m][n] = (f32x4){0.f,0.f,0.f,0.f};

  LOAD(0);
  for (int kk = 0; kk < IDIM/64; kk++){
    STORE();
    if (kk + 1 < IDIM/64) LOAD(kk+1);
    __syncthreads();
    #pragma unroll
    for (int ki = 0; ki < 2; ki++){
      bf16x8 af[4];
      #pragma unroll
      for (int m = 0; m < 4; m++){
        int row = wave_r*64 + m*16 + (lane&15);
        int slot = ki*4 + (lane>>4);
        af[m] = *reinterpret_cast<const bf16x8*>(sA + row*128 + ((slot ^ (row&7))<<4));
      }
      #pragma unroll
      for (int n = 0; n < 2; n++){
        int col = wave_c*32 + n*16 + (lane&15);
        int slot = ki*4 + (lane>>4);
        bf16x8 fb = *reinterpret_cast<const bf16x8*>(sB + col*128 + ((slot ^ (col&7))<<4));
        #pragma unroll
        for (int m = 0; m < 4; m++)
          acc[m][n] = MFMA16(af[m], fb, acc[m][n], 0,0,0);
      }
    }
    __syncthreads();
  }
  const int lcol = lane & 15, lrow4 = (lane >> 4) * 4;
  #pragma unroll
  for (int m = 0; m < 4; m++){
    #pragma unroll
    for (int n = 0; n < 2; n++){
      int gcol = col0 + wave_c*32 + n*16 + lcol;
      #pragma unroll
      for (int r = 0; r < 4; r++){
        int grow = row0 + wave_r*64 + m*16 + lrow4 + r;
        if (grow < rend){
          eo[(size_t)grow*HDIM + gcol] = acc[m][n][r] * wrow[grow];
        }
      }
    }
  }
}

// ---------------- Kernel 6: combine + residual ----------------
__global__ __launch_bounds__(256) void k_combine(
    const float* __restrict__ x, const float* __restrict__ eo,
    const int* __restrict__ slot_of, float* __restrict__ out)
{
  const int t = blockIdx.x, tid = threadIdx.x;
  const int s0 = slot_of[t*2], s1 = slot_of[t*2+1];
  float4 xv = reinterpret_cast<const float4*>(x)[t*256 + tid];
  float4 a  = reinterpret_cast<const float4*>(eo)[s0*256 + tid];
  float4 b  = reinterpret_cast<const float4*>(eo)[s1*256 + tid];
  float4 ov;
  ov.x = xv.x + a.x + b.x;
  ov.y = xv.y + a.y + b.y;
  ov.z = xv.z + a.z + b.z;
  ov.w = xv.w + a.w + b.w;
  reinterpret_cast<float4*>(out)[t*256 + tid] = ov;
}

extern "C" void kernel_launch(void* const* d_in, const int* in_sizes, int n_in,
                              void* d_out, int out_size, void* d_ws, size_t ws_size,
                              hipStream_t stream)
{
  const float* x    = (const float*)d_in[0];
  const float* rmsw = (const float*)d_in[1];
  const float* gw   = (const float*)d_in[2];
  const float* w1   = (const float*)d_in[3];
  const float* w2   = (const float*)d_in[4];
  const float* w3   = (const float*)d_in[5];
  float* out = (float*)d_out;

  char* ws = (char*)d_ws;
  size_t o = 0;
  auto alloc = [&](size_t bytes) -> void* {
    void* p = ws + o;
    o += (bytes + 255) & ~(size_t)255;
    return p;
  };
  unsigned short* h_bf   = (unsigned short*)alloc((size_t)T_TOK*HDIM*2);
  int*   topk_i          = (int*)  alloc(T_TOK*2*4);
  float* topk_w          = (float*)alloc(T_TOK*2*4);
  int*   counters        = (int*)  alloc(64*4);
  int*   token_of_row    = (int*)  alloc(NROWS*4);
  float* wrow            = (float*)alloc(NROWS*4);
  int*   slot_of         = (int*)  alloc(T_TOK*2*4);
  unsigned short* act    = (unsigned short*)alloc((size_t)NROWS*IDIM*2);
  float* eo              = (float*)alloc((size_t)NROWS*HDIM*4);
  int* count  = counters;
  int* cursor = counters + 8;
  int* offset = counters + 16;

  // bf16 weight staging area: w1bf+w3bf during mlp_in; w2bf reuses it after.
  const size_t wbf_bytes = (size_t)2 * WELEM * 2;   // 117.4 MB
  bool bfpath = (ws_size >= o + wbf_bytes);
  unsigned short* w1bfp = (unsigned short*)(ws + o);
  unsigned short* w3bfp = w1bfp + WELEM;
  unsigned short* w2bfp = w1bfp;                    // sequential reuse

  hipMemsetAsync(counters, 0, 64*4, stream);
  k_rms_router<<<T_TOK, 256, 0, stream>>>(x, rmsw, gw, h_bf, topk_i, topk_w, count);
  k_scan<<<1, 64, 0, stream>>>(count, offset);
  k_scatter<<<(T_TOK+255)/256, 256, 0, stream>>>(topk_i, topk_w, offset, cursor,
                                                 token_of_row, wrow, slot_of);
  if (bfpath){
    k_cvt<<<2048, 256, 0, stream>>>((const float4*)w1, (uint2*)w1bfp, WELEM/4);
    k_cvt<<<2048, 256, 0, stream>>>((const float4*)w3, (uint2*)w3bfp, WELEM/4);
    // mlp_in: 56 panels x 16 row-tiles x 8 experts = 7168 blocks
    k_mlp_in_bf<<<7168, 256, 0, stream>>>(h_bf, w1bfp, w3bfp, token_of_row,
                                          count, offset, act);
    k_cvt<<<2048, 256, 0, stream>>>((const float4*)w2, (uint2*)w2bfp, WELEM/4);
    // mlp_out: 16 panels x 16 row-tiles x 8 experts = 2048 blocks
    k_mlp_out_bf<<<2048, 256, 0, stream>>>(act, w2bfp, wrow, count, offset, eo);
  } else {
    k_mlp_in_fb <<<dim3(16, 56, 8), 256, 0, stream>>>(h_bf, w1, w3, token_of_row,
                                                      count, offset, act);
    k_mlp_out_fb<<<dim3(16, 16, 8), 256, 0, stream>>>(act, w2, wrow, count, offset, eo);
  }
  k_combine<<<T_TOK, 256, 0, stream>>>(x, eo, slot_of, out);
}